// Round 11
// baseline (276.853 us; speedup 1.0000x reference)
//
#include <hip/hip_runtime.h>
#include <hip/hip_bf16.h>

#define SEQ 2048
#define BSZ 2
#define DIM 1024
#define NH 16
#define HD 64
#define WIN 8
#define PN 256

typedef __hip_bfloat16 bf16;
typedef __attribute__((ext_vector_type(8))) short short8;
typedef __attribute__((ext_vector_type(4))) short short4v;
typedef __attribute__((ext_vector_type(4))) float f32x4;

__device__ __forceinline__ float b2f(bf16 x) { return __bfloat162float(x); }
__device__ __forceinline__ bf16 f2b(float x) { return __float2bfloat16(x); }
__device__ __forceinline__ short fbits(float x) { bf16 h = __float2bfloat16(x); return *(short*)&h; }

// async global->LDS, 16B per lane; LDS dest must be wave-uniform base + lane*16
__device__ __forceinline__ void gl_lds16(const bf16* g, bf16* l) {
    __builtin_amdgcn_global_load_lds((const __attribute__((address_space(1))) void*)g,
                                     (__attribute__((address_space(3))) void*)l, 16, 0, 0);
}

// ---------------------------------------------------------------------------
// fused pre-pass: fp32->bf16 query (4M) + 6 weights (6M) + bias pack +
// phrase max-pool (bf16 out).  Branching is block-granular (ranges aligned).
// ---------------------------------------------------------------------------
__global__ void convert_kernel(const float* __restrict__ q,
                               const float* __restrict__ w0, const float* __restrict__ w1,
                               const float* __restrict__ w2, const float* __restrict__ w3,
                               const float* __restrict__ w4, const float* __restrict__ w5,
                               const float* __restrict__ b0, const float* __restrict__ b1,
                               const float* __restrict__ b2, const float* __restrict__ b3,
                               const float* __restrict__ b4, const float* __restrict__ b5,
                               bf16* __restrict__ qbf, bf16* __restrict__ wbf,
                               float* __restrict__ bp, bf16* __restrict__ phrase) {
    int i = blockIdx.x * 256 + threadIdx.x;          // vector idx, 8 floats each
    const int QV = (SEQ * BSZ * DIM) / 8;            // 524288
    const int WV = (DIM * DIM) / 8;                  // 131072
    const int TV = QV + 6 * WV;                      // 1310720 (block-aligned)
    const int BVE = TV + 768;                        // bias end
    if (i < TV) {
        const float* src;
        bf16* dst;
        size_t off;
        if (i < QV) { src = q; dst = qbf; off = (size_t)i * 8; }
        else {
            int j = i - QV;
            int mat = j / WV, k = j - mat * WV;
            src = (mat == 0) ? w0 : (mat == 1) ? w1 : (mat == 2) ? w2
                : (mat == 3) ? w3 : (mat == 4) ? w4 : w5;
            dst = wbf + (size_t)mat * DIM * DIM;
            off = (size_t)k * 8;
        }
        f32x4 av4 = *(const f32x4*)(src + off);
        f32x4 bv4 = *(const f32x4*)(src + off + 4);
        short8 o;
#pragma unroll
        for (int e = 0; e < 4; ++e) { o[e] = fbits(av4[e]); o[e + 4] = fbits(bv4[e]); }
        *(short8*)(dst + off) = o;
    } else if (i < BVE) {                            // bias pack: 768 chunks
        int j = i - TV;
        int mat = j >> 7, k = (j & 127) * 8;
        const float* s = (mat == 0) ? b0 : (mat == 1) ? b1 : (mat == 2) ? b2
                       : (mat == 3) ? b3 : (mat == 4) ? b4 : b5;
        *(f32x4*)(bp + mat * DIM + k)     = *(const f32x4*)(s + k);
        *(f32x4*)(bp + mat * DIM + k + 4) = *(const f32x4*)(s + k + 4);
    } else {                                         // phrase max: 65536 chunks
        int j = i - BVE;
        if (j >= (PN * BSZ * DIM) / 8) return;
        int base = j * 8;
        int d0 = base % DIM;
        int pb = base / DIM;
        int b = pb % BSZ, p = pb / BSZ;
        const float* src = q + ((size_t)(p * WIN) * BSZ + b) * DIM + d0;
        f32x4 m0 = *(const f32x4*)src;
        f32x4 m1 = *(const f32x4*)(src + 4);
#pragma unroll
        for (int w = 1; w < WIN; ++w) {
            const float* r = src + (size_t)w * BSZ * DIM;
            f32x4 a0 = *(const f32x4*)r, a1 = *(const f32x4*)(r + 4);
#pragma unroll
            for (int e = 0; e < 4; ++e) { m0[e] = fmaxf(m0[e], a0[e]); m1[e] = fmaxf(m1[e], a1[e]); }
        }
        short8 o;
#pragma unroll
        for (int e = 0; e < 4; ++e) { o[e] = fbits(m0[e]); o[e + 4] = fbits(m1[e]); }
        *(short8*)(phrase + base) = o;
    }
}

// ---------------------------------------------------------------------------
// gvT[bh*HD+hd][p] = sum_j gauss(p,j) * vT[bh*HD+hd][j], banded |j-mu|<=15.5
// ---------------------------------------------------------------------------
__global__ void gauss_v_kernel(const bf16* __restrict__ vT, bf16* __restrict__ gvT) {
    int row = blockIdx.x;               // bh*HD + hd
    int p   = threadIdx.x;              // 0..255
    float mu = p * (float)WIN + (WIN - 1) * 0.5f;
    float acc = 0.f;
    int j0 = p * WIN - 12;
    const bf16* src = vT + (size_t)row * SEQ;
#pragma unroll
    for (int jj = 0; jj < 32; ++jj) {
        int j = j0 + jj;
        if (j < 0 || j >= SEQ) continue;
        float dd = (float)j - mu;
        acc += __expf(-dd * dd * 0.125f) * 0.199471140200716f * b2f(src[j]);
    }
    gvT[(size_t)row * PN + p] = f2b(acc);
}

// ---------------------------------------------------------------------------
// 128x128 GEMM body (m97 pattern): C = (A @ Wtile^T + bias) * scale
// bf16 in via global_load_lds(16B), fp32 MFMA accum, LDS [128][32] unpadded.
// modes: 0 head-scatter bf16, 2 transposed head-scatter bf16.
// ---------------------------------------------------------------------------
__device__ __forceinline__ void gemm_body(const bf16* __restrict__ A,
                                          const bf16* __restrict__ W,
                                          const float* __restrict__ bias,
                                          void* __restrict__ Cout,
                                          int m0, int n0, float scale,
                                          int mode, int LEN) {
    __shared__ bf16 As[128 * 32];
    __shared__ bf16 Ws[128 * 32];
    int t = threadIdx.x;
    int wave = t >> 6, lane = t & 63;
    int wm = (wave >> 1) * 64, wn = (wave & 1) * 64;
    int l15 = lane & 15, quad = lane >> 4;

    f32x4 acc[4][4] = {};

    for (int k0 = 0; k0 < DIM; k0 += 32) {
        {
            int c0 = t, c1 = t + 256;
            gl_lds16(A + (size_t)(m0 + (c0 >> 2)) * DIM + k0 + (c0 & 3) * 8, &As[c0 * 8]);
            gl_lds16(A + (size_t)(m0 + (c1 >> 2)) * DIM + k0 + (c1 & 3) * 8, &As[c1 * 8]);
            gl_lds16(W + (size_t)(n0 + (c0 >> 2)) * DIM + k0 + (c0 & 3) * 8, &Ws[c0 * 8]);
            gl_lds16(W + (size_t)(n0 + (c1 >> 2)) * DIM + k0 + (c1 & 3) * 8, &Ws[c1 * 8]);
        }
        __syncthreads();
        short8 af[4], bfr[4];
#pragma unroll
        for (int tm = 0; tm < 4; ++tm)
            af[tm] = *(short8*)&As[(wm + tm * 16 + l15) * 32 + quad * 8];
#pragma unroll
        for (int tn = 0; tn < 4; ++tn)
            bfr[tn] = *(short8*)&Ws[(wn + tn * 16 + l15) * 32 + quad * 8];
#pragma unroll
        for (int tm = 0; tm < 4; ++tm)
#pragma unroll
            for (int tn = 0; tn < 4; ++tn)
                acc[tm][tn] = __builtin_amdgcn_mfma_f32_16x16x32_bf16(af[tm], bfr[tn], acc[tm][tn], 0, 0, 0);
        __syncthreads();
    }

#pragma unroll
    for (int tm = 0; tm < 4; ++tm) {
        int mrow = m0 + wm + tm * 16 + quad * 4;
#pragma unroll
        for (int tn = 0; tn < 4; ++tn) {
            int n = n0 + wn + tn * 16 + l15;
            float bsv = bias[n];
#pragma unroll
            for (int r = 0; r < 4; ++r) {
                int m = mrow + r;
                float val = (acc[tm][tn][r] + bsv) * scale;
                int s = m / BSZ, b = m % BSZ;
                int h = n >> 6, hd = n & 63;
                if (mode == 0)
                    ((bf16*)Cout)[((size_t)(b * NH + h) * LEN + s) * HD + hd] = f2b(val);
                else
                    ((bf16*)Cout)[((size_t)(b * NH + h) * HD + hd) * LEN + s] = f2b(val);
            }
        }
    }
}

#define QSCALE (0.125f * 1.44269504088896f)   // fold log2(e) for exp2

// batched projections: z = 0:q_b 1:k_b 2:vT 3:q_g 4:k_g(phrase)
__global__ __launch_bounds__(256) void gemm_proj(const bf16* __restrict__ qbf,
                                                 const bf16* __restrict__ phrasebf,
                                                 const bf16* __restrict__ wbf,
                                                 const float* __restrict__ bias_pack,
                                                 bf16* __restrict__ q_b, bf16* __restrict__ k_b,
                                                 bf16* __restrict__ vT, bf16* __restrict__ q_g,
                                                 bf16* __restrict__ k_g) {
    int z = blockIdx.z;
    const bf16* A = qbf;
    bf16* C;
    int mode = 0, LEN = SEQ;
    float scale = 1.0f;
    switch (z) {
        case 0: C = q_b; scale = QSCALE; break;
        case 1: C = k_b; break;
        case 2: C = vT; mode = 2; break;
        case 3: C = q_g; scale = QSCALE; break;
        default:
            if (blockIdx.x >= 4) return;          // M = 512 for phrase GEMM
            A = phrasebf; C = k_g; LEN = PN; break;
    }
    gemm_body(A, wbf + (size_t)z * DIM * DIM, bias_pack + z * DIM, C,
              blockIdx.x * 128, blockIdx.y * 128, scale, mode, LEN);
}

// ---------------------------------------------------------------------------
// final GEMM: out = attn_bf @ Wo^T + bo (fp32), 64x128 tile -> 512 blocks.
// ---------------------------------------------------------------------------
__global__ __launch_bounds__(256) void gemm_final(const bf16* __restrict__ A,
                                                  const bf16* __restrict__ wbf,
                                                  const float* __restrict__ bias_pack,
                                                  float* __restrict__ out) {
    __shared__ bf16 As[64 * 32];
    __shared__ bf16 Ws[128 * 32];
    const bf16* W = wbf + (size_t)5 * DIM * DIM;
    const float* bias = bias_pack + 5 * DIM;
    int t = threadIdx.x;
    int m0 = blockIdx.x * 64, n0 = blockIdx.y * 128;
    int wave = t >> 6, lane = t & 63;
    int wm = (wave >> 1) * 32, wn = (wave & 1) * 64;
    int l15 = lane & 15, quad = lane >> 4;

    f32x4 acc[2][4] = {};

    for (int k0 = 0; k0 < DIM; k0 += 32) {
        {
            int c0 = t, c1 = t + 256;
            gl_lds16(A + (size_t)(m0 + (c0 >> 2)) * DIM + k0 + (c0 & 3) * 8, &As[c0 * 8]);
            gl_lds16(W + (size_t)(n0 + (c0 >> 2)) * DIM + k0 + (c0 & 3) * 8, &Ws[c0 * 8]);
            gl_lds16(W + (size_t)(n0 + (c1 >> 2)) * DIM + k0 + (c1 & 3) * 8, &Ws[c1 * 8]);
        }
        __syncthreads();
        short8 af[2], bfr[4];
#pragma unroll
        for (int tm = 0; tm < 2; ++tm)
            af[tm] = *(short8*)&As[(wm + tm * 16 + l15) * 32 + quad * 8];
#pragma unroll
        for (int tn = 0; tn < 4; ++tn)
            bfr[tn] = *(short8*)&Ws[(wn + tn * 16 + l15) * 32 + quad * 8];
#pragma unroll
        for (int tm = 0; tm < 2; ++tm)
#pragma unroll
            for (int tn = 0; tn < 4; ++tn)
                acc[tm][tn] = __builtin_amdgcn_mfma_f32_16x16x32_bf16(af[tm], bfr[tn], acc[tm][tn], 0, 0, 0);
        __syncthreads();
    }

#pragma unroll
    for (int tm = 0; tm < 2; ++tm) {
        int mrow = m0 + wm + tm * 16 + quad * 4;
#pragma unroll
        for (int tn = 0; tn < 4; ++tn) {
            int n = n0 + wn + tn * 16 + l15;
            float bsv = bias[n];
#pragma unroll
            for (int r = 0; r < 4; ++r)
                out[(size_t)(mrow + r) * DIM + n] = acc[tm][tn][r] + bsv;
        }
    }
}

// ---------------------------------------------------------------------------
// MFMA attention v5: v4 geometry (128 q-rows, 4 waves x 32 rows, 2x K/V frag
// reuse, P aliases own Q rows) + LDS DOUBLE-BUFFERED K/V -> ONE barrier per
// chunk.  Hazards: write[ch]->buf(ch&1) precedes barrier[ch]; compute[ch]
// reads buf(ch&1) after it; next write to that buf (ch+2) is after
// barrier[ch+1] which all readers passed.  VGPR prefetch covers global
// latency across the whole compute phase.  LDS 55.3 KB (grid-limited to
// 2 blocks/CU anyway).
// ---------------------------------------------------------------------------
__global__ __launch_bounds__(256) void attn_kernel(const bf16* __restrict__ qb,
                                                   const bf16* __restrict__ kb,
                                                   const bf16* __restrict__ vT,
                                                   const bf16* __restrict__ qg,
                                                   const bf16* __restrict__ kg,
                                                   const bf16* __restrict__ gvT,
                                                   bf16* __restrict__ out) {
    __shared__ bf16 QPs[128][72];     // Q during hoist, then Ps[qrow][key]
    __shared__ bf16 Ks[2][64][72];    // [buf][key][hd]
    __shared__ bf16 Vt[2][64][72];    // [buf][hd][key]

    int t = threadIdx.x;
    int wave = t >> 6, lane = t & 63;
    int l15 = lane & 15, quad = lane >> 4;
    int q0 = blockIdx.x * 128;
    int bh = blockIdx.y;
    int b = bh / NH, h = bh % NH;

    const short8 ones = (short8)0x3F80;   // bf16 1.0 splat

    float result[2][4][4] = {};           // [q-tile][n-tile][row]

    for (int phase = 0; phase < 2; ++phase) {
        const bf16* qptr = phase ? qb : qg;
        const bf16* kptr = phase ? kb : kg;
        const bf16* vtp  = phase ? vT : gvT;
        int kvlen = phase ? SEQ : PN;
        int nchunk = kvlen / 64;

        __syncthreads();   // prior phase's P reads done before Q restage
        {
            int r = t >> 1, c0 = (t & 1) * 32;
            const bf16* qsrc = qptr + ((size_t)bh * SEQ + q0 + r) * HD + c0;
#pragma unroll
            for (int e = 0; e < 4; ++e)
                *(short8*)&QPs[r][c0 + e * 8] = *(const short8*)(qsrc + e * 8);
        }
        __syncthreads();   // Q visible
        // hoist chunk-invariant Q B-fragments (this wave's 32 q-rows)
        short8 bq[2][2];   // [q-tile][kk]
#pragma unroll
        for (int qt = 0; qt < 2; ++qt) {
            bq[qt][0] = *(short8*)&QPs[wave * 32 + qt * 16 + l15][quad * 8];
            bq[qt][1] = *(short8*)&QPs[wave * 32 + qt * 16 + l15][32 + quad * 8];
        }

        int sr = t >> 2, sc = (t & 3) * 16;
        const bf16* kbase = kptr + ((size_t)bh * kvlen + sr) * HD + sc;
        const bf16* vbase = vtp + (size_t)(bh * HD + sr) * kvlen + sc;

        // prefetch chunk 0
        short8 kr0 = *(const short8*)(kbase);
        short8 kr1 = *(const short8*)(kbase + 8);
        short8 vr0 = *(const short8*)(vbase);
        short8 vr1 = *(const short8*)(vbase + 8);

        f32x4 o_acc[2][4] = {};
        f32x4 l_acc[2] = {};
        for (int ch = 0; ch < nchunk; ++ch) {
            int buf = ch & 1;
            // deposit prefetched chunk ch into its buffer (no pre-barrier:
            // this buffer's last readers finished before barrier[ch-1])
            *(short8*)&Ks[buf][sr][sc]     = kr0;
            *(short8*)&Ks[buf][sr][sc + 8] = kr1;
            *(short8*)&Vt[buf][sr][sc]     = vr0;
            *(short8*)&Vt[buf][sr][sc + 8] = vr1;
            if (ch + 1 < nchunk) {     // prefetch chunk ch+1 over compute
                const bf16* kn = kbase + (size_t)(ch + 1) * 64 * HD;
                const bf16* vn = vbase + (ch + 1) * 64;
                kr0 = *(const short8*)(kn);
                kr1 = *(const short8*)(kn + 8);
                vr0 = *(const short8*)(vn);
                vr1 = *(const short8*)(vn + 8);
            }
            __syncthreads();   // the ONE barrier: buf writes visible

            // S^T = K Q^T : D[m=key (4 tiles)][n=qrow (2 tiles of 16)]
            f32x4 s_acc[2][4] = {};
#pragma unroll
            for (int kk = 0; kk < 2; ++kk) {
#pragma unroll
                for (int tn = 0; tn < 4; ++tn) {
                    short8 ak = *(short8*)&Ks[buf][tn * 16 + l15][kk * 32 + quad * 8];
                    s_acc[0][tn] = __builtin_amdgcn_mfma_f32_16x16x32_bf16(ak, bq[0][kk], s_acc[0][tn], 0, 0, 0);
                    s_acc[1][tn] = __builtin_amdgcn_mfma_f32_16x16x32_bf16(ak, bq[1][kk], s_acc[1][tn], 0, 0, 0);
                }
            }
            // P = exp2(S^T): col=qrow(l15), reg->key -> packed 8B row-major store
#pragma unroll
            for (int qt = 0; qt < 2; ++qt)
#pragma unroll
                for (int tn = 0; tn < 4; ++tn) {
                    short4v pk;
#pragma unroll
                    for (int r = 0; r < 4; ++r)
                        pk[r] = fbits(exp2f(s_acc[qt][tn][r]));
                    *(short4v*)&QPs[wave * 32 + qt * 16 + l15][tn * 16 + quad * 4] = pk;
                }
            // PV + rowsum: A = P rows (own wave's), B = Vt rows (reused 2x)
#pragma unroll
            for (int kk = 0; kk < 2; ++kk) {
                short8 pa0 = *(short8*)&QPs[wave * 32 + l15][kk * 32 + quad * 8];
                short8 pa1 = *(short8*)&QPs[wave * 32 + 16 + l15][kk * 32 + quad * 8];
                l_acc[0] = __builtin_amdgcn_mfma_f32_16x16x32_bf16(pa0, ones, l_acc[0], 0, 0, 0);
                l_acc[1] = __builtin_amdgcn_mfma_f32_16x16x32_bf16(pa1, ones, l_acc[1], 0, 0, 0);
#pragma unroll
                for (int tn = 0; tn < 4; ++tn) {
                    short8 vb = *(short8*)&Vt[buf][tn * 16 + l15][kk * 32 + quad * 8];
                    o_acc[0][tn] = __builtin_amdgcn_mfma_f32_16x16x32_bf16(pa0, vb, o_acc[0][tn], 0, 0, 0);
                    o_acc[1][tn] = __builtin_amdgcn_mfma_f32_16x16x32_bf16(pa1, vb, o_acc[1][tn], 0, 0, 0);
                }
            }
        }
#pragma unroll
        for (int qt = 0; qt < 2; ++qt)
#pragma unroll
            for (int r = 0; r < 4; ++r) {
                float inv = 0.5f / fmaxf(l_acc[qt][r], 1e-30f);
#pragma unroll
                for (int tn = 0; tn < 4; ++tn)
                    result[qt][tn][r] += o_acc[qt][tn][r] * inv;
            }
    }

    // store attn_bf; O C-layout: col=hd(l15), row=qrow quad*4+r
#pragma unroll
    for (int qt = 0; qt < 2; ++qt)
#pragma unroll
        for (int r = 0; r < 4; ++r) {
            int srow = q0 + wave * 32 + qt * 16 + quad * 4 + r;
            int mm = srow * BSZ + b;
#pragma unroll
            for (int tn = 0; tn < 4; ++tn) {
                int dcol = h * HD + tn * 16 + l15;
                out[(size_t)mm * DIM + dcol] = f2b(result[qt][tn][r]);
            }
        }
}

// ---------------------------------------------------------------------------
extern "C" void kernel_launch(void* const* d_in, const int* in_sizes, int n_in,
                              void* d_out, int out_size, void* d_ws, size_t ws_size,
                              hipStream_t stream) {
    (void)in_sizes; (void)n_in; (void)out_size; (void)ws_size;
    const float* query = (const float*)d_in[0];
    const float* Wq_b  = (const float*)d_in[1];
    const float* bq_b  = (const float*)d_in[2];
    const float* Wk_b  = (const float*)d_in[3];
    const float* bk_b  = (const float*)d_in[4];
    const float* Wq_g  = (const float*)d_in[5];
    const float* bq_g  = (const float*)d_in[6];
    const float* Wk_g  = (const float*)d_in[7];
    const float* bk_g  = (const float*)d_in[8];
    const float* Wv    = (const float*)d_in[9];
    const float* bv    = (const float*)d_in[10];
    const float* Wo    = (const float*)d_in[11];
    const float* bo    = (const float*)d_in[12];
    float* out = (float*)d_out;

    const size_t NQ = (size_t)BSZ * NH * SEQ * HD;   // 4194304
    const size_t NP = (size_t)BSZ * NH * PN * HD;    // 524288
    bf16* qbf      = (bf16*)d_ws;                    // 4M
    bf16* wbf      = qbf + NQ;                       // 6M
    bf16* phrasebf = wbf + (size_t)6 * DIM * DIM;    // 512K
    bf16* q_b      = phrasebf + (size_t)PN * BSZ * DIM;
    bf16* k_b      = q_b + NQ;
    bf16* vT       = k_b + NQ;                       // [bh][hd][s]
    bf16* q_g      = vT + NQ;
    bf16* k_g      = q_g + NQ;                       // [bh][p][hd]
    bf16* gvT      = k_g + NP;                       // [bh][hd][p]
    bf16* attn_bf  = gvT + NP;                       // [m][dcol]
    float* bias_pack = (float*)(attn_bf + NQ);       // 6*1024 fp32

    const int QV = (SEQ * BSZ * DIM) / 8, WV6 = 6 * (DIM * DIM) / 8;
    const int PHV = (PN * BSZ * DIM) / 8;
    int nconv = (QV + WV6 + 768 + PHV + 255) / 256;
    convert_kernel<<<nconv, 256, 0, stream>>>(
        query, Wq_b, Wk_b, Wv, Wq_g, Wk_g, Wo,
        bq_b, bk_b, bv, bq_g, bk_g, bo, qbf, wbf, bias_pack, phrasebf);

    dim3 gp((SEQ * BSZ) / 128, DIM / 128, 5);
    gemm_proj<<<gp, 256, 0, stream>>>(qbf, phrasebf, wbf, bias_pack,
                                      q_b, k_b, vT, q_g, k_g);

    gauss_v_kernel<<<BSZ * NH * HD, PN, 0, stream>>>(vT, gvT);

    dim3 g3(SEQ / 128, BSZ * NH);
    attn_kernel<<<g3, 256, 0, stream>>>(q_b, k_b, vT, q_g, k_g, gvT, attn_bf);

    dim3 gf((SEQ * BSZ) / 64, DIM / 128);
    gemm_final<<<gf, 256, 0, stream>>>(attn_bf, wbf, bias_pack, out);
}